// Round 7
// baseline (391.071 us; speedup 1.0000x reference)
//
#include <hip/hip_runtime.h>
#include <stdint.h>

#define T_LEN 512
#define HIDN  32
#define GW    128
#define VOCAB 101
#define GP    132   // G pitch (bf16/row), layout [v][unit*4+gate], gate order i,f,g,o
#define HP    56    // h pitch in bf16
#define XPB   516   // packed-u8 x pitch in bytes

typedef short short8 __attribute__((ext_vector_type(8)));
typedef float f32x4  __attribute__((ext_vector_type(4)));

#define LOG2E 1.442695041f

__device__ __forceinline__ float bf2f(uint16_t u) {
    union { uint32_t i; float f; } x; x.i = ((uint32_t)u) << 16; return x.f;
}
__device__ __forceinline__ uint16_t f2bf(float f) {
    union { float f; uint32_t i; } x; x.f = f;
    return (uint16_t)((x.i + 0x7FFFu + ((x.i >> 16) & 1u)) >> 16);
}
__device__ __forceinline__ float asF(uint32_t u) {
    union { uint32_t i; float f; } x; x.i = u; return x.f;
}
__device__ __forceinline__ float bf_lo(uint32_t u) { return asF(u << 16); }
__device__ __forceinline__ float bf_hi(uint32_t u) { return asF(u & 0xFFFF0000u); }
__device__ __forceinline__ float sigm2(float xs) {
    return __builtin_amdgcn_rcpf(1.f + __builtin_amdgcn_exp2f(-xs));
}
__device__ __forceinline__ float tanh2s(float ys) {   // ys = log2e * y
    return 1.f - 2.f * __builtin_amdgcn_rcpf(__builtin_amdgcn_exp2f(ys + ys) + 1.f);
}
__device__ __forceinline__ float tanh2t(float y) {    // true-scale y (cell state)
    return 1.f - 2.f * __builtin_amdgcn_rcpf(__builtin_amdgcn_exp2f(2.885390082f * y) + 1.f);
}
__device__ __forceinline__ float getw(const void* p, int i, bool isbf) {
    return isbf ? bf2f(((const uint16_t*)p)[i]) : ((const float*)p)[i];
}
__device__ __forceinline__ bool detect_bf16(const void* embp) {
    const uint16_t* u = (const uint16_t*)embp;
    int sane = 0;
    for (int i = 0; i < 64; ++i) {
        uint16_t v = u[i];
        int e = (v >> 7) & 0xFF;
        sane += ((e >= 100 && e <= 140) || ((v & 0x7FFFu) == 0)) ? 1 : 0;
    }
    return sane >= 56;
}

// Round-3 kernel (validated at 1 ULP), re-gridded: 8 batch rows/block, grid 512
// -> 2 blocks/CU, 8 waves/CU. Rows 8-15 of all structures mirror rows 0-7
// (duplicate compute, unused results). Per-row arithmetic bit-identical to r3.
__global__ __launch_bounds__(256) void lstm_fused(
    const int* __restrict__ x, const void* __restrict__ emb,
    const void* __restrict__ Wx, const void* __restrict__ Wh,
    const void* __restrict__ bias, const void* __restrict__ Wfc,
    const void* __restrict__ bfc, void* __restrict__ out)
{
    __shared__ __align__(16) uint16_t G_l[VOCAB * GP];   // 26,664 B
    __shared__ __align__(16) uint8_t  xt8[16 * XPB];     //  8,256 B (emb scratch at init)
    __shared__ __align__(16) uint16_t hbuf[2 * 16 * HP]; //  3,584 B double-buffered h

    const int tid = threadIdx.x;
    const int wl  = tid & 63;
    const int w   = tid >> 6;       // wave 0..3 -> owns units 8w..8w+7
    const int n   = wl & 15;        // batch row (rows 8-15 duplicate 0-7)
    const int q   = wl >> 4;        // MFMA k-quad
    const int b0  = blockIdx.x * 8; // 8 real rows per block

    const bool isbf = detect_bf16(emb);

    // ---- stage emb (bf16) into xt8 scratch ----
    {
        uint16_t* embL = (uint16_t*)xt8;
        for (int i = tid; i < VOCAB * 32; i += 256)
            embL[i] = isbf ? ((const uint16_t*)emb)[i] : f2bf(((const float*)emb)[i]);
    }
    __syncthreads();
    // ---- build G: G[v][u*4+g] = log2e * (emb[v]@Wx + b)[32g+u], bf16 ----
    {
        const uint16_t* embL = (const uint16_t*)xt8;
        for (int idx = tid; idx < VOCAB * GW; idx += 256) {
            int v = idx >> 7, col = idx & 127;
            float acc = getw(bias, col, isbf);
            #pragma unroll 8
            for (int k = 0; k < 32; ++k)
                acc += bf2f(embL[v * 32 + k]) * getw(Wx, k * GW + col, isbf);
            G_l[v * GP + ((col & 31) << 2) + (col >> 5)] = f2bf(acc * LOG2E);
        }
    }
    __syncthreads();   // emb scratch dead; xt8 reusable
    // ---- pack x tokens to u8 for all 512 steps (row clamped to the 8 real rows) ----
    for (int i = tid; i < 2048; i += 256) {         // 16 rows * 128 int4
        int row = i >> 7, c4 = i & 127;
        int4 vv = *(const int4*)&x[(b0 + (row & 7)) * T_LEN + (c4 << 2)];
        uint32_t p = (uint32_t)(vv.x & 255) | ((uint32_t)(vv.y & 255) << 8) |
                     ((uint32_t)(vv.z & 255) << 16) | ((uint32_t)(vv.w & 255) << 24);
        ((uint32_t*)&xt8[row * XPB])[c4] = p;
    }
    // ---- zero h buffers ----
    for (int i = tid; i < 2 * 16 * HP; i += 256) hbuf[i] = 0;

    // ---- A-fragments: A_j[m=n][k=8q+jj] = log2e * Wh[8q+jj][32*(n&3) + 4*jt + (n>>2)] ----
    short8 afr0, afr1;
    {
        union { short8 v; uint16_t s[8]; } u0, u1;
        int oc0 = 32 * (n & 3) + 4 * (2 * w)     + (n >> 2);
        int oc1 = 32 * (n & 3) + 4 * (2 * w + 1) + (n >> 2);
        #pragma unroll
        for (int jj = 0; jj < 8; ++jj) {
            int k = 8 * q + jj;
            u0.s[jj] = f2bf(getw(Wh, k * GW + oc0, isbf) * LOG2E);
            u1.s[jj] = f2bf(getw(Wh, k * GW + oc1, isbf) * LOG2E);
        }
        afr0 = u0.v; afr1 = u1.v;
    }
    __syncthreads();

    const int u0i = 8 * w + q;       // lane's unit from tile 2w
    const int u1i = 8 * w + 4 + q;   // lane's unit from tile 2w+1
    float c0 = 0.f, c1 = 0.f;

    // prefetch G for t=0
    uint32_t gA0, gA1, gB0, gB1;
    {
        int v = xt8[n * XPB];
        const uint32_t* g = (const uint32_t*)&G_l[v * GP];
        gA0 = g[u0i * 2]; gA1 = g[u0i * 2 + 1];
        gB0 = g[u1i * 2]; gB1 = g[u1i * 2 + 1];
    }

    for (int t = 0; t < T_LEN; ++t) {
        const uint16_t* hr = &hbuf[(t & 1) * (16 * HP)];
        uint16_t*       hw = &hbuf[((t & 1) ^ 1) * (16 * HP)];
        // B fragment: h(t-1)[n][8q..8q+7]
        short8 bfrag = *(const short8*)&hr[n * HP + 8 * q];
        f32x4 s0 = {0.f, 0.f, 0.f, 0.f};
        f32x4 s1 = {0.f, 0.f, 0.f, 0.f};
        s0 = __builtin_amdgcn_mfma_f32_16x16x32_bf16(afr0, bfrag, s0, 0, 0, 0);
        s1 = __builtin_amdgcn_mfma_f32_16x16x32_bf16(afr1, bfrag, s1, 0, 0, 0);
        // prefetch G for t+1 (depends only on x -> overlaps MFMA latency)
        int vn = xt8[n * XPB + ((t + 1) & (T_LEN - 1))];
        const uint32_t* gnx = (const uint32_t*)&G_l[vn * GP];
        uint32_t nA0 = gnx[u0i * 2], nA1 = gnx[u0i * 2 + 1];
        uint32_t nB0 = gnx[u1i * 2], nB1 = gnx[u1i * 2 + 1];
        // gates, unit0 (acc regs r = i,f,g,o)
        {
            float pi = s0[0] + bf_lo(gA0), pf = s0[1] + bf_hi(gA0);
            float pg = s0[2] + bf_lo(gA1), po = s0[3] + bf_hi(gA1);
            c0 = sigm2(pf) * c0 + sigm2(pi) * tanh2s(pg);
            hw[n * HP + u0i] = f2bf(sigm2(po) * tanh2t(c0));
        }
        // gates, unit1
        {
            float pi = s1[0] + bf_lo(gB0), pf = s1[1] + bf_hi(gB0);
            float pg = s1[2] + bf_lo(gB1), po = s1[3] + bf_hi(gB1);
            c1 = sigm2(pf) * c1 + sigm2(pi) * tanh2s(pg);
            hw[n * HP + u1i] = f2bf(sigm2(po) * tanh2t(c1));
        }
        gA0 = nA0; gA1 = nA1; gB0 = nB0; gB1 = nB1;
        __syncthreads();
    }

    // ---- epilogue: out = h(T-1) @ W_fc + b_fc ; h(511) lives in buf 0; 8 real rows ----
    if (tid < 16) {
        int row = tid >> 1, cc = tid & 1;
        float acc = getw(bfc, cc, isbf);
        #pragma unroll 8
        for (int k = 0; k < HIDN; ++k)
            acc += bf2f(hbuf[row * HP + k]) * getw(Wfc, k * 2 + cc, isbf);
        int oidx = (b0 + row) * 2 + cc;
        if (isbf) ((uint16_t*)out)[oidx] = f2bf(acc);
        else      ((float*)out)[oidx]    = acc;
    }
}

extern "C" void kernel_launch(void* const* d_in, const int* in_sizes, int n_in,
                              void* d_out, int out_size, void* d_ws, size_t ws_size,
                              hipStream_t stream) {
    (void)in_sizes; (void)n_in; (void)d_ws; (void)ws_size; (void)out_size;
    const int* x = (const int*)d_in[0];
    lstm_fused<<<dim3(512), dim3(256), 0, stream>>>(
        x, d_in[1], d_in[2], d_in[3], d_in[4], d_in[5], d_in[6], d_out);
}

// Round 8
// 374.718 us; speedup vs baseline: 1.0436x; 1.0436x over previous
//
#include <hip/hip_runtime.h>
#include <stdint.h>

#define T_LEN 512
#define HIDN  32
#define GW    128
#define VOCAB 101
#define GP    132   // G pitch (bf16/row), layout [v][unit*4+gate], gate order i,f,g,o
#define XPB   516   // packed-u8 x pitch in bytes

typedef short short8 __attribute__((ext_vector_type(8)));
typedef float f32x4  __attribute__((ext_vector_type(4)));

#define LOG2E 1.442695041f

__device__ __forceinline__ float bf2f(uint16_t u) {
    union { uint32_t i; float f; } x; x.i = ((uint32_t)u) << 16; return x.f;
}
__device__ __forceinline__ uint16_t f2bf(float f) {
    union { float f; uint32_t i; } x; x.f = f;
    return (uint16_t)((x.i + 0x7FFFu + ((x.i >> 16) & 1u)) >> 16);
}
__device__ __forceinline__ float asF(uint32_t u) {
    union { uint32_t i; float f; } x; x.i = u; return x.f;
}
__device__ __forceinline__ float bf_lo(uint32_t u) { return asF(u << 16); }
__device__ __forceinline__ float bf_hi(uint32_t u) { return asF(u & 0xFFFF0000u); }
__device__ __forceinline__ float sigm2(float xs) {
    return __builtin_amdgcn_rcpf(1.f + __builtin_amdgcn_exp2f(-xs));
}
__device__ __forceinline__ float tanh2s(float ys) {   // ys = log2e * y
    return 1.f - 2.f * __builtin_amdgcn_rcpf(__builtin_amdgcn_exp2f(ys + ys) + 1.f);
}
__device__ __forceinline__ float tanh2t(float y) {    // true-scale y (cell state)
    return 1.f - 2.f * __builtin_amdgcn_rcpf(__builtin_amdgcn_exp2f(2.885390082f * y) + 1.f);
}
__device__ __forceinline__ float getw(const void* p, int i, bool isbf) {
    return isbf ? bf2f(((const uint16_t*)p)[i]) : ((const float*)p)[i];
}
__device__ __forceinline__ bool detect_bf16(const void* embp) {
    const uint16_t* u = (const uint16_t*)embp;
    int sane = 0;
    for (int i = 0; i < 64; ++i) {
        uint16_t v = u[i];
        int e = (v >> 7) & 0xFF;
        sane += ((e >= 100 && e <= 140) || ((v & 0x7FFFu) == 0)) ? 1 : 0;
    }
    return sane >= 56;
}

// r3-validated arithmetic, new topology: wave w owns batch rows 4w..4w+3 fully
// (all 32 units). All step-loop dataflow is intra-wave -> NO barrier in the loop.
// Per-wave: 8 MFMA tiles (4 valid cols), private LDS D-exchange, 2 updates/lane.
__global__ __launch_bounds__(256) void lstm_fused(
    const int* __restrict__ x, const void* __restrict__ emb,
    const void* __restrict__ Wx, const void* __restrict__ Wh,
    const void* __restrict__ bias, const void* __restrict__ Wfc,
    const void* __restrict__ bfc, void* __restrict__ out)
{
    __shared__ __align__(16) uint16_t G_l[VOCAB * GP];   // 26,664 B
    __shared__ __align__(16) uint8_t  xt8[16 * XPB];     //  8,256 B (emb scratch at init)
    __shared__ __align__(16) uint16_t hb[4 * 128];       //  1,024 B [wave][row4][unit32]
    __shared__ __align__(16) float    dex[4 * 512];      //  8,192 B [wave][slot128][f32x4]

    const int tid = threadIdx.x;
    const int wl  = tid & 63;
    const int w   = tid >> 6;        // wave 0..3 -> batch rows 4w..4w+3
    const int n   = wl & 15;         // MFMA A-row / D-col lane role
    const int q   = wl >> 4;         // MFMA k-quad / D-row-quad
    const int b0  = blockIdx.x * 16;

    const bool isbf = detect_bf16(emb);

    // ---- stage emb (bf16) into xt8 scratch ----
    {
        uint16_t* embL = (uint16_t*)xt8;
        for (int i = tid; i < VOCAB * 32; i += 256)
            embL[i] = isbf ? ((const uint16_t*)emb)[i] : f2bf(((const float*)emb)[i]);
    }
    __syncthreads();
    // ---- build G: G[v][u*4+g] = log2e * (emb[v]@Wx + b)[32g+u], bf16 ----
    {
        const uint16_t* embL = (const uint16_t*)xt8;
        for (int idx = tid; idx < VOCAB * GW; idx += 256) {
            int v = idx >> 7, col = idx & 127;
            float acc = getw(bias, col, isbf);
            #pragma unroll 8
            for (int k = 0; k < 32; ++k)
                acc += bf2f(embL[v * 32 + k]) * getw(Wx, k * GW + col, isbf);
            G_l[v * GP + ((col & 31) << 2) + (col >> 5)] = f2bf(acc * LOG2E);
        }
    }
    __syncthreads();   // emb scratch dead; xt8 reusable
    // ---- pack x tokens to u8 for all 512 steps (16 real rows) ----
    for (int i = tid; i < 2048; i += 256) {         // 16 rows * 128 int4
        int row = i >> 7, c4 = i & 127;
        int4 vv = *(const int4*)&x[(b0 + row) * T_LEN + (c4 << 2)];
        uint32_t p = (uint32_t)(vv.x & 255) | ((uint32_t)(vv.y & 255) << 8) |
                     ((uint32_t)(vv.z & 255) << 16) | ((uint32_t)(vv.w & 255) << 24);
        ((uint32_t*)&xt8[row * XPB])[c4] = p;
    }
    // ---- zero h ----
    for (int i = tid; i < 256; i += 256) ((uint32_t*)hb)[i] = 0u;

    // ---- A-fragments, 8 tiles: tile jt covers units 4jt..4jt+3
    //      A[m=n][k=8q+jj] = log2e * Wh[8q+jj][32*(n&3) + 4*jt + (n>>2)] ----
    short8 afr[8];
    #pragma unroll
    for (int jt = 0; jt < 8; ++jt) {
        union { short8 v; uint16_t s[8]; } u0;
        int oc = 32 * (n & 3) + 4 * jt + (n >> 2);
        #pragma unroll
        for (int jj = 0; jj < 8; ++jj)
            u0.s[jj] = f2bf(getw(Wh, (8 * q + jj) * GW + oc, isbf) * LOG2E);
        afr[jt] = u0.v;
    }
    __syncthreads();

    // per-lane update role: row r (of this wave's 4), units U0, U0+1
    const int r  = wl & 3;
    const int U0 = 2 * (wl >> 2);
    uint16_t* hbw = &hb[w * 128];
    float*    dxw = &dex[w * 512];
    const uint8_t* xb = &xt8[(4 * w + r) * XPB];
    float c0 = 0.f, c1 = 0.f;

    // G prefetch for t=0: units U0, U0+1 -> 2x uint2 (i,f | g,o dwords)
    uint2 gA, gB;
    {
        int v = xb[0];
        gA = *(const uint2*)&G_l[v * GP + U0 * 4];
        gB = *(const uint2*)&G_l[v * GP + U0 * 4 + 4];
    }
    const f32x4 zero4 = {0.f, 0.f, 0.f, 0.f};

    #pragma unroll 2
    for (int t = 0; t < T_LEN; ++t) {
        // B-frag: h(t-1)[row n&3][8q..8q+7] from this wave's private h
        short8 bfrag = *(const short8*)&hbw[(n & 3) * 32 + 8 * q];
        f32x4 acc[8];
        #pragma unroll
        for (int jt = 0; jt < 8; ++jt)
            acc[jt] = __builtin_amdgcn_mfma_f32_16x16x32_bf16(afr[jt], bfrag, zero4, 0, 0, 0);
        // D exchange (intra-wave): lanes with valid col n<4 scatter gates of
        // (unit 4jt+q, row n) to slot idx 64jt+16q+4n (f32x4, conflict-free)
        if (n < 4) {
            #pragma unroll
            for (int jt = 0; jt < 8; ++jt)
                *(f32x4*)&dxw[64 * jt + 16 * q + 4 * n] = acc[jt];
        }
        // prefetch G for t+1 (depends only on x)
        int vn = xb[(t + 1) & (T_LEN - 1)];
        uint2 nA = *(const uint2*)&G_l[vn * GP + U0 * 4];
        uint2 nB = *(const uint2*)&G_l[vn * GP + U0 * 4 + 4];
        // my two units' preacts (slot = 16*U + 4*r)
        f32x4 s0 = *(const f32x4*)&dxw[16 * U0 + 4 * r];
        f32x4 s1 = *(const f32x4*)&dxw[16 * U0 + 4 * r + 16];
        // unit U0
        float h0, h1;
        {
            float pi = s0[0] + bf_lo(gA.x), pf = s0[1] + bf_hi(gA.x);
            float pg = s0[2] + bf_lo(gA.y), po = s0[3] + bf_hi(gA.y);
            c0 = sigm2(pf) * c0 + sigm2(pi) * tanh2s(pg);
            h0 = sigm2(po) * tanh2t(c0);
        }
        // unit U0+1
        {
            float pi = s1[0] + bf_lo(gB.x), pf = s1[1] + bf_hi(gB.x);
            float pg = s1[2] + bf_lo(gB.y), po = s1[3] + bf_hi(gB.y);
            c1 = sigm2(pf) * c1 + sigm2(pi) * tanh2s(pg);
            h1 = sigm2(po) * tanh2t(c1);
        }
        // h write: 2 adjacent bf16 units, single b32 (single-buffered: read of t
        // already completed in-order before this write)
        ((uint32_t*)hbw)[(r * 32 + U0) >> 1] =
            (uint32_t)f2bf(h0) | ((uint32_t)f2bf(h1) << 16);
        gA = nA; gB = nB;
    }
    __syncthreads();

    // ---- epilogue: out = h(T-1) @ W_fc + b_fc (16 real rows) ----
    if (tid < 32) {
        int row = tid >> 1, cc = tid & 1;
        float acc = getw(bfc, cc, isbf);
        const uint16_t* hrow = &hb[(row >> 2) * 128 + (row & 3) * 32];
        #pragma unroll 8
        for (int k = 0; k < HIDN; ++k)
            acc += bf2f(hrow[k]) * getw(Wfc, k * 2 + cc, isbf);
        int oidx = (b0 + row) * 2 + cc;
        if (isbf) ((uint16_t*)out)[oidx] = f2bf(acc);
        else      ((float*)out)[oidx]    = acc;
    }
}

extern "C" void kernel_launch(void* const* d_in, const int* in_sizes, int n_in,
                              void* d_out, int out_size, void* d_ws, size_t ws_size,
                              hipStream_t stream) {
    (void)in_sizes; (void)n_in; (void)d_ws; (void)ws_size; (void)out_size;
    const int* x = (const int*)d_in[0];
    lstm_fused<<<dim3(256), dim3(256), 0, stream>>>(
        x, d_in[1], d_in[2], d_in[3], d_in[4], d_in[5], d_in[6], d_out);
}